// Round 9
// baseline (254.113 us; speedup 1.0000x reference)
//
#include <hip/hip_runtime.h>
#include <hip/hip_bf16.h>
#include <stdint.h>

// RBF dense layer: out[b][u] = exp(-gamma * max(|x_b|^2 + |k_u|^2 - 2*x_b.k_u, 0)) + bias[u]
// B=8192, D=512, U=4096, fp32 in/out. gamma = 1.0.
// Round 9: BM=256 x BN=128, BK=64, 512 thr (8 waves 4x2, wave-tile 64x64,
// acc[4][4]), SINGLE-buffered 48 KiB LDS -> 2 blocks/CU co-resident
// (16 waves/CU, 4/SIMD — 2x round-8) forced via __launch_bounds__(512,4).
// Operand re-fetch 512->384 MB. 3-bit involution LDS swizzle (conflict-free),
// XCD swizzle, setprio. Full vmcnt(0) drains (8 steps -> ~2us total, cheap).

using short8 = __attribute__((ext_vector_type(8))) short;
using bf16x8 = __attribute__((ext_vector_type(8))) __bf16;
using f32x4  = __attribute__((ext_vector_type(4))) float;
typedef unsigned short ushort_t;

#define GAMMA_F 1.0f

__device__ __forceinline__ ushort_t f2bf(float f) {
  unsigned u = __float_as_uint(f);
  u = (u + 0x7fffu + ((u >> 16) & 1u)) >> 16;  // RNE
  return (ushort_t)u;
}

// ---- merged prep ----
// blocks [0,2048): x rows -> xb bf16 [8192][512] + xsq
// blocks [2048,2112): kernel [512][4096] -> kbT bf16 [4096][512] + ksq
__global__ __launch_bounds__(256) void prep_kernel(
    const float* __restrict__ x, const float* __restrict__ kern,
    ushort_t* __restrict__ xb, ushort_t* __restrict__ kbT,
    float* __restrict__ xsq, float* __restrict__ ksq) {
  const int t = threadIdx.x;
  if (blockIdx.x < 2048) {
    const int w = t >> 6, l = t & 63;
    const int r = blockIdx.x * 4 + w;
    const float4* xr = (const float4*)(x + (size_t)r * 512);
    float4 v0 = xr[l * 2 + 0];
    float4 v1 = xr[l * 2 + 1];
    float s = v0.x * v0.x + v0.y * v0.y + v0.z * v0.z + v0.w * v0.w
            + v1.x * v1.x + v1.y * v1.y + v1.z * v1.z + v1.w * v1.w;
    short8 p;
    p[0] = (short)f2bf(v0.x); p[1] = (short)f2bf(v0.y);
    p[2] = (short)f2bf(v0.z); p[3] = (short)f2bf(v0.w);
    p[4] = (short)f2bf(v1.x); p[5] = (short)f2bf(v1.y);
    p[6] = (short)f2bf(v1.z); p[7] = (short)f2bf(v1.w);
    *(short8*)(xb + (size_t)r * 512 + l * 8) = p;
#pragma unroll
    for (int o = 32; o > 0; o >>= 1) s += __shfl_xor(s, o);
    if (l == 0) xsq[r] = s;
  } else {
    __shared__ ushort_t tile[64][65];
    __shared__ float red[4][64];
    const int u0 = (blockIdx.x - 2048) * 64;
    const int c = t & 63, tq = t >> 6;
    float part = 0.f;
    for (int d0 = 0; d0 < 512; d0 += 64) {
#pragma unroll
      for (int i = 0; i < 16; ++i) {
        const int r = tq * 16 + i;
        const float v = kern[(size_t)(d0 + r) * 4096 + u0 + c];
        part += v * v;
        tile[r][c] = f2bf(v);
      }
      __syncthreads();
      const int dl = (t & 7) * 8;
#pragma unroll
      for (int h = 0; h < 2; ++h) {
        const int ul = (t >> 3) + h * 32;
        short8 v;
#pragma unroll
        for (int j = 0; j < 8; ++j) ((ushort_t*)&v)[j] = tile[dl + j][ul];
        *(short8*)(kbT + (size_t)(u0 + ul) * 512 + d0 + dl) = v;
      }
      __syncthreads();
    }
    red[tq][c] = part;
    __syncthreads();
    if (t < 64) ksq[u0 + t] = red[0][t] + red[1][t] + red[2][t] + red[3][t];
  }
}

// ---- 256x128 single-buffered GEMM + fused RBF epilogue ----
// 512 thr = 8 waves: wr = w>>1 in 0..3 (rows), wc = w&1 (cols). Wave 64x64 out.
// LDS: A [256][64] = 32 KiB + B [128][64] = 16 KiB = 48 KiB -> 2 blocks/CU.
// Per K-step: STAGE (6 gload_lds: 4 A + 2 B) -> __syncthreads (vmcnt drain) ->
// 16 ds_read_b128 -> 32 MFMA (setprio) -> __syncthreads.
// Swizzle: physical 16B chunk = logical ^ (row&7); pre-swizzled global source,
// linear gload_lds dest, same XOR on ds_read (involution; row&7 == l&7).
__global__ __launch_bounds__(512, 4) void rbf_gemm_kernel(
    const ushort_t* __restrict__ xb, const ushort_t* __restrict__ kbT,
    const float* __restrict__ xsq, const float* __restrict__ ksq,
    const float* __restrict__ bias, float* __restrict__ out) {
  __shared__ ushort_t A_lds[256 * 64];  // 32 KiB
  __shared__ ushort_t B_lds[128 * 64];  // 16 KiB

  const int tid = threadIdx.x;
  const int w = tid >> 6, l = tid & 63;
  const int wr = w >> 1, wc = w & 1;

  // T1: bijective XCD swizzle (nwg=1024, 1024%8==0, q=128)
  const int wgid = ((blockIdx.x & 7) << 7) + (blockIdx.x >> 3);
  const int brow = (wgid >> 5) * 256;  // 32 row-tiles; consecutive ids share brow
  const int bcol = (wgid & 31) * 128;  // 32 col-tiles

  // staging: thread t -> row t>>3 (+i*64 per issue), chunk t&7 pre-swizzled
  const int srow = tid >> 3;                      // 0..63
  const int sj = (tid & 7) ^ ((tid >> 3) & 7);    // involution on 16B chunks
  const ushort_t* gA0 = xb  + (size_t)(brow + srow) * 512 + sj * 8;
  const ushort_t* gB0 = kbT + (size_t)(bcol + srow) * 512 + sj * 8;
  const int ldsw = w * 512;  // wave-uniform: wave w covers rows i*64+w*8..+7

#define STAGE_TILE(kt) do {                                                       \
    const ushort_t* _ga = gA0 + (size_t)(kt) * 64;                                \
    const ushort_t* _gb = gB0 + (size_t)(kt) * 64;                                \
    _Pragma("unroll")                                                             \
    for (int i = 0; i < 4; ++i)                                                   \
      __builtin_amdgcn_global_load_lds(                                           \
          (const __attribute__((address_space(1))) void*)(_ga + (size_t)i * 32768),\
          (__attribute__((address_space(3))) void*)(&A_lds[i * 4096 + ldsw]), 16, 0, 0); \
    _Pragma("unroll")                                                             \
    for (int i = 0; i < 2; ++i)                                                   \
      __builtin_amdgcn_global_load_lds(                                           \
          (const __attribute__((address_space(1))) void*)(_gb + (size_t)i * 32768),\
          (__attribute__((address_space(3))) void*)(&B_lds[i * 4096 + ldsw]), 16, 0, 0); \
  } while (0)

  // ds_read: A row = wr*64 + f*16 + l15 (row&7 == l7), B row = wc*64 + n*16 + l15.
  // logical chunk (k/8) = ks*4 + l4; physical = (logical ^ l7) * 8 elems.
  const int l15 = l & 15, l4 = l >> 4, l7 = l & 7;
  const int chk0 = (l4 ^ l7) * 8;        // k in [0,32)
  const int chk1 = ((4 + l4) ^ l7) * 8;  // k in [32,64)
  const int aoff = (wr * 64 + l15) * 64;
  const int boff = (wc * 64 + l15) * 64;

  f32x4 acc[4][4] = {};

  for (int s = 0; s < 8; ++s) {
    STAGE_TILE(s);
    __syncthreads();  // vmcnt(0)+lgkmcnt(0) drain + barrier (compiler-emitted)

    bf16x8 a0[4], a1[4], b0[4], b1[4];
#pragma unroll
    for (int m = 0; m < 4; ++m) {
      a0[m] = *(const bf16x8*)&A_lds[aoff + m * 1024 + chk0];
      a1[m] = *(const bf16x8*)&A_lds[aoff + m * 1024 + chk1];
    }
#pragma unroll
    for (int n = 0; n < 4; ++n) {
      b0[n] = *(const bf16x8*)&B_lds[boff + n * 1024 + chk0];
      b1[n] = *(const bf16x8*)&B_lds[boff + n * 1024 + chk1];
    }
    __builtin_amdgcn_s_setprio(1);
#pragma unroll
    for (int m = 0; m < 4; ++m)
#pragma unroll
      for (int n = 0; n < 4; ++n)
        acc[m][n] = __builtin_amdgcn_mfma_f32_16x16x32_bf16(a0[m], b0[n], acc[m][n], 0, 0, 0);
#pragma unroll
    for (int m = 0; m < 4; ++m)
#pragma unroll
      for (int n = 0; n < 4; ++n)
        acc[m][n] = __builtin_amdgcn_mfma_f32_16x16x32_bf16(a1[m], b1[n], acc[m][n], 0, 0, 0);
    __builtin_amdgcn_s_setprio(0);
    __syncthreads();  // all reads done before next STAGE overwrites
  }

  // epilogue: C/D frag layout col=lane&15, row=(lane>>4)*4+reg (m89/m91)
  const int cl = l15, rg = l4 * 4;
#pragma unroll
  for (int n = 0; n < 4; ++n) {
    const int gc = bcol + wc * 64 + n * 16 + cl;
    const float kq = ksq[gc];
    const float bz = bias[gc];
#pragma unroll
    for (int m = 0; m < 4; ++m) {
      const int gr0 = brow + wr * 64 + m * 16 + rg;
      const float4 xq = *(const float4*)&xsq[gr0];
      const float xq4[4] = {xq.x, xq.y, xq.z, xq.w};
#pragma unroll
      for (int j = 0; j < 4; ++j) {
        float d2 = xq4[j] + kq - 2.0f * acc[m][n][j];
        d2 = fmaxf(d2, 0.0f);
        out[(size_t)(gr0 + j) * 4096 + gc] = __expf(-GAMMA_F * d2) + bz;
      }
    }
  }
#undef STAGE_TILE
}

// ---- fallback (ws too small): direct fp32 ----
__global__ __launch_bounds__(256) void rbf_direct_kernel(
    const float* __restrict__ x, const float* __restrict__ kern,
    const float* __restrict__ bias, float* __restrict__ out) {
  __shared__ float Xs[64][17];
  __shared__ float Ks[16][65];
  const int tid = threadIdx.x;
  const int brow = blockIdx.y * 64, bcol = blockIdx.x * 64;
  const int tr = (tid >> 4) * 4, tc = (tid & 15) * 4;
  float acc[4][4] = {};
  for (int k0 = 0; k0 < 512; k0 += 16) {
    {
      const int r = tid >> 2, c = (tid & 3) * 4;
      float4 v = *(const float4*)&x[(size_t)(brow + r) * 512 + k0 + c];
      Xs[r][c] = v.x; Xs[r][c + 1] = v.y; Xs[r][c + 2] = v.z; Xs[r][c + 3] = v.w;
    }
    {
      const int r = tid >> 4, c = (tid & 15) * 4;
      float4 v = *(const float4*)&kern[(size_t)(k0 + r) * 4096 + bcol + c];
      Ks[r][c] = v.x; Ks[r][c + 1] = v.y; Ks[r][c + 2] = v.z; Ks[r][c + 3] = v.w;
    }
    __syncthreads();
#pragma unroll
    for (int kk = 0; kk < 16; ++kk) {
      float a[4], b[4];
#pragma unroll
      for (int i = 0; i < 4; ++i) a[i] = Xs[tr + i][kk];
#pragma unroll
      for (int j = 0; j < 4; ++j) b[j] = Ks[kk][tc + j];
#pragma unroll
      for (int i = 0; i < 4; ++i)
#pragma unroll
        for (int j = 0; j < 4; ++j) {
          float d = a[i] - b[j];
          acc[i][j] = fmaf(d, d, acc[i][j]);
        }
    }
    __syncthreads();
  }
#pragma unroll
  for (int i = 0; i < 4; ++i)
#pragma unroll
    for (int j = 0; j < 4; ++j)
      out[(size_t)(brow + tr + i) * 4096 + bcol + tc + j] =
          __expf(-GAMMA_F * acc[i][j]) + bias[bcol + tc + j];
}

extern "C" void kernel_launch(void* const* d_in, const int* in_sizes, int n_in,
                              void* d_out, int out_size, void* d_ws, size_t ws_size,
                              hipStream_t stream) {
  const float* x    = (const float*)d_in[0];   // 8192*512
  const float* kern = (const float*)d_in[1];   // 512*4096
  const float* bias = (const float*)d_in[2];   // 4096
  float* out = (float*)d_out;                  // 8192*4096 f32

  const size_t NEED = 8388608 /*xb*/ + 4194304 /*kbT*/ + 32768 /*xsq*/ + 16384 /*ksq*/;
  if (ws_size < NEED) {
    rbf_direct_kernel<<<dim3(64, 128), 256, 0, stream>>>(x, kern, bias, out);
    return;
  }

  char* ws = (char*)d_ws;
  ushort_t* xb  = (ushort_t*)(ws);                 // 8 MiB bf16 x
  ushort_t* kbT = (ushort_t*)(ws + 8388608);       // 4 MiB bf16 kernel^T
  float* xsq = (float*)(ws + 8388608 + 4194304);   // 32 KiB row norms
  float* ksq = xsq + 8192;                         // 16 KiB col norms

  prep_kernel<<<2112, 256, 0, stream>>>(x, kern, xb, kbT, xsq, ksq);
  rbf_gemm_kernel<<<1024, 512, 0, stream>>>(xb, kbT, xsq, ksq, bias, out);
}

// Round 10
// 214.013 us; speedup vs baseline: 1.1874x; 1.1874x over previous
//
#include <hip/hip_runtime.h>
#include <hip/hip_bf16.h>
#include <stdint.h>

// RBF dense layer: out[b][u] = exp(-gamma * max(|x_b|^2 + |k_u|^2 - 2*x_b.k_u, 0)) + bias[u]
// B=8192, D=512, U=4096, fp32 in/out. gamma = 1.0.
// Round 10: r4 geometry (256x256, 1 blk/CU, best measured L2 traffic: FETCH 42
// + WRITE 149 MB) x r8 sync (single stage + counted vmcnt + 2 barriers/K-step,
// minimal 24 ds_reads). Epilogue: n-innermost (adjacent half-line stores) +
// nontemporal stores. XCD swizzle, involution LDS swizzle, setprio.

using short8 = __attribute__((ext_vector_type(8))) short;
using bf16x8 = __attribute__((ext_vector_type(8))) __bf16;
using f32x4  = __attribute__((ext_vector_type(4))) float;
typedef unsigned short ushort_t;

#define GAMMA_F 1.0f

__device__ __forceinline__ ushort_t f2bf(float f) {
  unsigned u = __float_as_uint(f);
  u = (u + 0x7fffu + ((u >> 16) & 1u)) >> 16;  // RNE
  return (ushort_t)u;
}

// ---- merged prep ----
// blocks [0,2048): x rows -> xb bf16 [8192][512] + xsq
// blocks [2048,2112): kernel [512][4096] -> kbT bf16 [4096][512] + ksq
__global__ __launch_bounds__(256) void prep_kernel(
    const float* __restrict__ x, const float* __restrict__ kern,
    ushort_t* __restrict__ xb, ushort_t* __restrict__ kbT,
    float* __restrict__ xsq, float* __restrict__ ksq) {
  const int t = threadIdx.x;
  if (blockIdx.x < 2048) {
    const int w = t >> 6, l = t & 63;
    const int r = blockIdx.x * 4 + w;
    const float4* xr = (const float4*)(x + (size_t)r * 512);
    float4 v0 = xr[l * 2 + 0];
    float4 v1 = xr[l * 2 + 1];
    float s = v0.x * v0.x + v0.y * v0.y + v0.z * v0.z + v0.w * v0.w
            + v1.x * v1.x + v1.y * v1.y + v1.z * v1.z + v1.w * v1.w;
    short8 p;
    p[0] = (short)f2bf(v0.x); p[1] = (short)f2bf(v0.y);
    p[2] = (short)f2bf(v0.z); p[3] = (short)f2bf(v0.w);
    p[4] = (short)f2bf(v1.x); p[5] = (short)f2bf(v1.y);
    p[6] = (short)f2bf(v1.z); p[7] = (short)f2bf(v1.w);
    *(short8*)(xb + (size_t)r * 512 + l * 8) = p;
#pragma unroll
    for (int o = 32; o > 0; o >>= 1) s += __shfl_xor(s, o);
    if (l == 0) xsq[r] = s;
  } else {
    __shared__ ushort_t tile[64][65];
    __shared__ float red[4][64];
    const int u0 = (blockIdx.x - 2048) * 64;
    const int c = t & 63, tq = t >> 6;
    float part = 0.f;
    for (int d0 = 0; d0 < 512; d0 += 64) {
#pragma unroll
      for (int i = 0; i < 16; ++i) {
        const int r = tq * 16 + i;
        const float v = kern[(size_t)(d0 + r) * 4096 + u0 + c];
        part += v * v;
        tile[r][c] = f2bf(v);
      }
      __syncthreads();
      const int dl = (t & 7) * 8;
#pragma unroll
      for (int h = 0; h < 2; ++h) {
        const int ul = (t >> 3) + h * 32;
        short8 v;
#pragma unroll
        for (int j = 0; j < 8; ++j) ((ushort_t*)&v)[j] = tile[dl + j][ul];
        *(short8*)(kbT + (size_t)(u0 + ul) * 512 + d0 + dl) = v;
      }
      __syncthreads();
    }
    red[tq][c] = part;
    __syncthreads();
    if (t < 64) ksq[u0 + t] = red[0][t] + red[1][t] + red[2][t] + red[3][t];
  }
}

// ---- 256x256 double-buffered GEMM + fused RBF epilogue ----
// 512 thr = 8 waves: wr = w>>2 in {0,1} (row half), wc = w&3 (col quarter).
// Wave-tile 128x64: acc[8][4]. LDS: A,B each [2dbuf][256][64] = 64 KiB ->
// 128 KiB total, 1 blk/CU (r4's proven L2-resident geometry; grid 512 = 2/CU).
// Per K-step: STAGE next tile (8 gload_lds) -> vmcnt(8) -> barrier ->
// 24 ds_read_b128 (B once, A per m-group) + 64 MFMA (setprio) -> barrier.
__global__ __launch_bounds__(512, 2) void rbf_gemm_kernel(
    const ushort_t* __restrict__ xb, const ushort_t* __restrict__ kbT,
    const float* __restrict__ xsq, const float* __restrict__ ksq,
    const float* __restrict__ bias, float* __restrict__ out) {
  __shared__ ushort_t A_lds[2 * 256 * 64];  // 64 KiB
  __shared__ ushort_t B_lds[2 * 256 * 64];  // 64 KiB

  const int tid = threadIdx.x;
  const int w = tid >> 6, l = tid & 63;
  const int wr = w >> 2, wc = w & 3;

  // T1: bijective XCD swizzle (nwg=512, 512%8==0, q=64)
  const int wgid = ((blockIdx.x & 7) << 6) + (blockIdx.x >> 3);
  const int brow = (wgid >> 4) * 256;  // 32 row-tiles; consecutive ids share brow
  const int bcol = (wgid & 15) * 256;  // 16 col-tiles

  // staging: thread t -> row t>>3 (+i*64 per issue), chunk t&7 pre-swizzled
  const int srow = tid >> 3;
  const int sj = (tid & 7) ^ ((tid >> 3) & 7);
  const ushort_t* gA0 = xb  + (size_t)(brow + srow) * 512 + sj * 8;
  const ushort_t* gB0 = kbT + (size_t)(bcol + srow) * 512 + sj * 8;
  const int ldsw = w * 512;  // wave-uniform LDS base per issue

#define STAGE_TILE(kt, dn) do {                                                   \
    const ushort_t* _ga = gA0 + (size_t)(kt) * 64;                                \
    const ushort_t* _gb = gB0 + (size_t)(kt) * 64;                                \
    const int _lb = (dn) * 16384 + ldsw;                                          \
    _Pragma("unroll")                                                             \
    for (int i = 0; i < 4; ++i)                                                   \
      __builtin_amdgcn_global_load_lds(                                           \
          (const __attribute__((address_space(1))) void*)(_ga + (size_t)i * 32768),\
          (__attribute__((address_space(3))) void*)(&A_lds[_lb + i * 4096]), 16, 0, 0); \
    _Pragma("unroll")                                                             \
    for (int i = 0; i < 4; ++i)                                                   \
      __builtin_amdgcn_global_load_lds(                                           \
          (const __attribute__((address_space(1))) void*)(_gb + (size_t)i * 32768),\
          (__attribute__((address_space(3))) void*)(&B_lds[_lb + i * 4096]), 16, 0, 0); \
  } while (0)

  // ds_read: A row = wr*128 + m*16 + l15, B row = wc*64 + n*16 + l15; row&7==l7.
  // logical chunk (k/8) = ks*4 + l4; physical = (logical ^ l7) * 8 elems.
  const int l15 = l & 15, l4 = l >> 4, l7 = l & 7;
  const int chk0 = (l4 ^ l7) * 8;        // k in [0,32)
  const int chk1 = ((4 + l4) ^ l7) * 8;  // k in [32,64)
  const int aoff = (wr * 128 + l15) * 64;
  const int boff = (wc * 64 + l15) * 64;

  f32x4 acc[8][4] = {};

  // prologue: stage K-tile 0 -> dbuf 0 (8 loads in flight)
  STAGE_TILE(0, 0);

#pragma unroll 2
  for (int s = 0; s < 8; ++s) {
    const int dbase = (s & 1) * 16384;
    // issue next tile into the other dbuf (fully consumed at step s-1's trailing
    // barrier); counted wait: 16 outstanding -> wait to 8 = current tile done.
    STAGE_TILE((s + 1) & 7, (s + 1) & 1);
    asm volatile("s_waitcnt vmcnt(8)" ::: "memory");
    asm volatile("s_barrier" ::: "memory");

    // B fragments once (8 reads, 32 VGPR), A per m-group (2 reads + 8 MFMA)
    bf16x8 b0[4], b1[4];
#pragma unroll
    for (int n = 0; n < 4; ++n) {
      b0[n] = *(const bf16x8*)&B_lds[dbase + boff + n * 1024 + chk0];
      b1[n] = *(const bf16x8*)&B_lds[dbase + boff + n * 1024 + chk1];
    }
    __builtin_amdgcn_s_setprio(1);
#pragma unroll
    for (int m = 0; m < 8; ++m) {
      bf16x8 a0 = *(const bf16x8*)&A_lds[dbase + aoff + m * 1024 + chk0];
      bf16x8 a1 = *(const bf16x8*)&A_lds[dbase + aoff + m * 1024 + chk1];
#pragma unroll
      for (int n = 0; n < 4; ++n)
        acc[m][n] = __builtin_amdgcn_mfma_f32_16x16x32_bf16(a0, b0[n], acc[m][n], 0, 0, 0);
#pragma unroll
      for (int n = 0; n < 4; ++n)
        acc[m][n] = __builtin_amdgcn_mfma_f32_16x16x32_bf16(a1, b1[n], acc[m][n], 0, 0, 0);
    }
    __builtin_amdgcn_s_setprio(0);
    __builtin_amdgcn_sched_barrier(0);
    asm volatile("s_barrier" ::: "memory");  // reads done before next overwrite
  }

  // epilogue: C/D frag layout col=lane&15, row=(lane>>4)*4+reg (m89/m91).
  // n innermost so the two 64B half-lines of each 128B line are adjacent
  // stores; nontemporal to cut L2 write-allocate pressure.
  const int cl = l15, rg = l4 * 4;
  float kq[4], bz[4];
  int gcn[4];
#pragma unroll
  for (int n = 0; n < 4; ++n) {
    gcn[n] = bcol + wc * 64 + n * 16 + cl;
    kq[n] = ksq[gcn[n]];
    bz[n] = bias[gcn[n]];
  }
#pragma unroll
  for (int m = 0; m < 8; ++m) {
    const int gr0 = brow + wr * 128 + m * 16 + rg;
    const float4 xq = *(const float4*)&xsq[gr0];
    const float xq4[4] = {xq.x, xq.y, xq.z, xq.w};
#pragma unroll
    for (int j = 0; j < 4; ++j) {
      float* orow = out + (size_t)(gr0 + j) * 4096;
#pragma unroll
      for (int n = 0; n < 4; ++n) {
        float d2 = xq4[j] + kq[n] - 2.0f * acc[m][n][j];
        d2 = fmaxf(d2, 0.0f);
        __builtin_nontemporal_store(__expf(-GAMMA_F * d2) + bz[n], &orow[gcn[n]]);
      }
    }
  }
#undef STAGE_TILE
}

// ---- fallback (ws too small): direct fp32 ----
__global__ __launch_bounds__(256) void rbf_direct_kernel(
    const float* __restrict__ x, const float* __restrict__ kern,
    const float* __restrict__ bias, float* __restrict__ out) {
  __shared__ float Xs[64][17];
  __shared__ float Ks[16][65];
  const int tid = threadIdx.x;
  const int brow = blockIdx.y * 64, bcol = blockIdx.x * 64;
  const int tr = (tid >> 4) * 4, tc = (tid & 15) * 4;
  float acc[4][4] = {};
  for (int k0 = 0; k0 < 512; k0 += 16) {
    {
      const int r = tid >> 2, c = (tid & 3) * 4;
      float4 v = *(const float4*)&x[(size_t)(brow + r) * 512 + k0 + c];
      Xs[r][c] = v.x; Xs[r][c + 1] = v.y; Xs[r][c + 2] = v.z; Xs[r][c + 3] = v.w;
    }
    {
      const int r = tid >> 4, c = (tid & 15) * 4;
      float4 v = *(const float4*)&kern[(size_t)(k0 + r) * 4096 + bcol + c];
      Ks[r][c] = v.x; Ks[r][c + 1] = v.y; Ks[r][c + 2] = v.z; Ks[r][c + 3] = v.w;
    }
    __syncthreads();
#pragma unroll
    for (int kk = 0; kk < 16; ++kk) {
      float a[4], b[4];
#pragma unroll
      for (int i = 0; i < 4; ++i) a[i] = Xs[tr + i][kk];
#pragma unroll
      for (int j = 0; j < 4; ++j) b[j] = Ks[kk][tc + j];
#pragma unroll
      for (int i = 0; i < 4; ++i)
#pragma unroll
        for (int j = 0; j < 4; ++j) {
          float d = a[i] - b[j];
          acc[i][j] = fmaf(d, d, acc[i][j]);
        }
    }
    __syncthreads();
  }
#pragma unroll
  for (int i = 0; i < 4; ++i)
#pragma unroll
    for (int j = 0; j < 4; ++j)
      out[(size_t)(brow + tr + i) * 4096 + bcol + tc + j] =
          __expf(-GAMMA_F * acc[i][j]) + bias[bcol + tc + j];
}

extern "C" void kernel_launch(void* const* d_in, const int* in_sizes, int n_in,
                              void* d_out, int out_size, void* d_ws, size_t ws_size,
                              hipStream_t stream) {
  const float* x    = (const float*)d_in[0];   // 8192*512
  const float* kern = (const float*)d_in[1];   // 512*4096
  const float* bias = (const float*)d_in[2];   // 4096
  float* out = (float*)d_out;                  // 8192*4096 f32

  const size_t NEED = 8388608 /*xb*/ + 4194304 /*kbT*/ + 32768 /*xsq*/ + 16384 /*ksq*/;
  if (ws_size < NEED) {
    rbf_direct_kernel<<<dim3(64, 128), 256, 0, stream>>>(x, kern, bias, out);
    return;
  }

  char* ws = (char*)d_ws;
  ushort_t* xb  = (ushort_t*)(ws);                 // 8 MiB bf16 x
  ushort_t* kbT = (ushort_t*)(ws + 8388608);       // 4 MiB bf16 kernel^T
  float* xsq = (float*)(ws + 8388608 + 4194304);   // 32 KiB row norms
  float* ksq = xsq + 8192;                         // 16 KiB col norms

  prep_kernel<<<2112, 256, 0, stream>>>(x, kern, xb, kbT, xsq, ksq);
  rbf_gemm_kernel<<<512, 512, 0, stream>>>(xb, kbT, xsq, ksq, bias, out);
}

// Round 13
// 166.773 us; speedup vs baseline: 1.5237x; 1.2833x over previous
//
#include <hip/hip_runtime.h>
#include <hip/hip_bf16.h>
#include <stdint.h>

// RBF dense layer: out[b][u] = exp(-gamma*|x_b - k_u|^2) + bias[u].
// B=8192, D=512, U=4096, fp32. gamma = 1.0.
// Insight: exp(-d2) underflows to exactly +0.0f whenever d2 >= 110
// (e^-110 ~ 1.6e-48 < 2^-150, below smallest subnormal). Reverse triangle
// inequality certifies d2 >= (|x_b| - |k_u|)^2 per pair. So: compute norms,
// per 64x256 output tile check gamma*(min_b|x| - max_u|k|)^2 >= 110 -> whole
// tile is exactly bias (write-stream). Exact fp32 fallback per tile where the
// bound fails (never for the bench distribution: min diff ~21.5 vs needed
// ~10.5). Removes the GEMM: 24 MB read + 128 MB write ~= 28 us of HBM time.

#define GAMMA_F 1.0f
#define D2_UNDERFLOW 110.0f   // exp(-110) == +0.0f in fp32 (incl. subnormals)

using f32x4 = __attribute__((ext_vector_type(4))) float;

// ---- pass 1: row norms |x_b| and col norms |k_u| ----
// blocks [0,2048): 4 x-rows each, wave per row (2x 16B/lane, shfl reduce)
// blocks [2048,2176): 32 kernel-cols each; 8 d-lanes x 32 cols, LDS reduce
__global__ __launch_bounds__(256) void norms_kernel(
    const float* __restrict__ x, const float* __restrict__ kern,
    float* __restrict__ sx, float* __restrict__ sk) {
  const int t = threadIdx.x;
  if (blockIdx.x < 2048) {
    const int w = t >> 6, l = t & 63;
    const int r = blockIdx.x * 4 + w;
    const f32x4* xr = (const f32x4*)(x + (size_t)r * 512);
    const f32x4 v0 = xr[l * 2 + 0];
    const f32x4 v1 = xr[l * 2 + 1];
    float s = v0.x * v0.x + v0.y * v0.y + v0.z * v0.z + v0.w * v0.w
            + v1.x * v1.x + v1.y * v1.y + v1.z * v1.z + v1.w * v1.w;
#pragma unroll
    for (int o = 32; o > 0; o >>= 1) s += __shfl_xor(s, o);
    if (l == 0) sx[r] = sqrtf(s);
  } else {
    __shared__ float red[8][32];
    const int b = blockIdx.x - 2048;   // 0..127
    const int dq = t >> 5;             // 0..7
    const int c = t & 31;
    const int u = b * 32 + c;
    float part = 0.f;
#pragma unroll 8
    for (int d = dq; d < 512; d += 8) {
      const float v = kern[(size_t)d * 4096 + u];  // 128B contiguous per dq-group
      part = fmaf(v, v, part);
    }
    red[dq][c] = part;
    __syncthreads();
    if (t < 32) {
      float s = red[0][t] + red[1][t] + red[2][t] + red[3][t]
              + red[4][t] + red[5][t] + red[6][t] + red[7][t];
      sk[b * 32 + t] = sqrtf(s);
    }
  }
}

// ---- pass 2: per-tile bound check + bias stream (fast) / exact RBF (slow) ----
// tile = 64 rows x 256 cols; grid 2048 blocks, 256 thr.
__global__ __launch_bounds__(256) void rbf_write_kernel(
    const float* __restrict__ x, const float* __restrict__ kern,
    const float* __restrict__ sx, const float* __restrict__ sk,
    const float* __restrict__ bias, float* __restrict__ out) {
  const int t = threadIdx.x;
  const int row0 = (blockIdx.x >> 4) * 64;
  const int col0 = (blockIdx.x & 15) * 256;
  const int w = t >> 6, l = t & 63;

  __shared__ float warpmax[4];
  __shared__ float s_min;
  __shared__ int s_fast;

  // max |k_u| over the 256 cols (one col per thread, per-wave shfl-max)
  float mx = sk[col0 + t];
#pragma unroll
  for (int o = 32; o > 0; o >>= 1) mx = fmaxf(mx, __shfl_xor(mx, o));
  if (l == 0) warpmax[w] = mx;
  // min |x_b| over the 64 rows (wave 0)
  if (w == 0) {
    float mn = sx[row0 + l];
#pragma unroll
    for (int o = 32; o > 0; o >>= 1) mn = fminf(mn, __shfl_xor(mn, o));
    if (l == 0) s_min = mn;
  }
  __syncthreads();
  if (t == 0) {
    const float mk = fmaxf(fmaxf(warpmax[0], warpmax[1]),
                           fmaxf(warpmax[2], warpmax[3]));
    const float diff = s_min - mk;
    // every pair in tile: d2 >= diff^2 >= 110/gamma  =>  exp == +0.0f exactly
    s_fast = (diff > 0.f) && (GAMMA_F * diff * diff >= D2_UNDERFLOW);
  }
  __syncthreads();

  const int cq = 4 * (t & 63);  // col offset within tile; wave covers 1KB
  if (s_fast) {
    const f32x4 bz = *(const f32x4*)&bias[col0 + cq];
    // 16 rows per thread, fully-coalesced nontemporal 16B stream
#pragma unroll
    for (int i = 0; i < 16; ++i) {
      f32x4* p = (f32x4*)(out + (size_t)(row0 + w + 4 * i) * 4096 + col0 + cq);
      __builtin_nontemporal_store(bz, p);
    }
  } else {
    // exact fp32 path (bound failed): d2 = sum_d (x-k)^2, direct
    const f32x4 bz = *(const f32x4*)&bias[col0 + cq];
    for (int i = 0; i < 16; ++i) {
      const int r = row0 + w + 4 * i;  // wave-uniform row
      float a0 = 0.f, a1 = 0.f, a2 = 0.f, a3 = 0.f;
      for (int d = 0; d < 512; ++d) {
        const float xv = x[(size_t)r * 512 + d];          // wave-broadcast
        const f32x4 kv = *(const f32x4*)&kern[(size_t)d * 4096 + col0 + cq];
        const float e0 = xv - kv.x, e1 = xv - kv.y, e2 = xv - kv.z, e3 = xv - kv.w;
        a0 = fmaf(e0, e0, a0); a1 = fmaf(e1, e1, a1);
        a2 = fmaf(e2, e2, a2); a3 = fmaf(e3, e3, a3);
      }
      f32x4 o;
      o.x = expf(-GAMMA_F * a0) + bz.x;
      o.y = expf(-GAMMA_F * a1) + bz.y;
      o.z = expf(-GAMMA_F * a2) + bz.z;
      o.w = expf(-GAMMA_F * a3) + bz.w;
      *(f32x4*)(out + (size_t)r * 4096 + col0 + cq) = o;
    }
  }
}

// ---- fallback (ws too small): direct fp32, no workspace ----
__global__ __launch_bounds__(256) void rbf_direct_kernel(
    const float* __restrict__ x, const float* __restrict__ kern,
    const float* __restrict__ bias, float* __restrict__ out) {
  __shared__ float Xs[64][17];
  __shared__ float Ks[16][65];
  const int tid = threadIdx.x;
  const int brow = blockIdx.y * 64, bcol = blockIdx.x * 64;
  const int tr = (tid >> 4) * 4, tc = (tid & 15) * 4;
  float acc[4][4] = {};
  for (int k0 = 0; k0 < 512; k0 += 16) {
    {
      const int r = tid >> 2, c = (tid & 3) * 4;
      f32x4 v = *(const f32x4*)&x[(size_t)(brow + r) * 512 + k0 + c];
      Xs[r][c] = v.x; Xs[r][c + 1] = v.y; Xs[r][c + 2] = v.z; Xs[r][c + 3] = v.w;
    }
    {
      const int r = tid >> 4, c = (tid & 15) * 4;
      f32x4 v = *(const f32x4*)&kern[(size_t)(k0 + r) * 4096 + bcol + c];
      Ks[r][c] = v.x; Ks[r][c + 1] = v.y; Ks[r][c + 2] = v.z; Ks[r][c + 3] = v.w;
    }
    __syncthreads();
#pragma unroll
    for (int kk = 0; kk < 16; ++kk) {
      float a[4], b[4];
#pragma unroll
      for (int i = 0; i < 4; ++i) a[i] = Xs[tr + i][kk];
#pragma unroll
      for (int j = 0; j < 4; ++j) b[j] = Ks[kk][tc + j];
#pragma unroll
      for (int i = 0; i < 4; ++i)
#pragma unroll
        for (int j = 0; j < 4; ++j) {
          float d = a[i] - b[j];
          acc[i][j] = fmaf(d, d, acc[i][j]);
        }
    }
    __syncthreads();
  }
#pragma unroll
  for (int i = 0; i < 4; ++i)
#pragma unroll
    for (int j = 0; j < 4; ++j)
      out[(size_t)(brow + tr + i) * 4096 + bcol + tc + j] =
          expf(-GAMMA_F * acc[i][j]) + bias[bcol + tc + j];
}

extern "C" void kernel_launch(void* const* d_in, const int* in_sizes, int n_in,
                              void* d_out, int out_size, void* d_ws, size_t ws_size,
                              hipStream_t stream) {
  const float* x    = (const float*)d_in[0];   // 8192*512
  const float* kern = (const float*)d_in[1];   // 512*4096
  const float* bias = (const float*)d_in[2];   // 4096
  float* out = (float*)d_out;                  // 8192*4096 f32

  const size_t NEED = 8192 * 4 + 4096 * 4;     // sx + sk = 48 KiB
  if (ws_size < NEED) {
    rbf_direct_kernel<<<dim3(64, 128), 256, 0, stream>>>(x, kern, bias, out);
    return;
  }

  float* sx = (float*)d_ws;        // 8192 row norms |x_b|
  float* sk = sx + 8192;           // 4096 col norms |k_u|

  norms_kernel<<<2176, 256, 0, stream>>>(x, kern, sx, sk);
  rbf_write_kernel<<<2048, 256, 0, stream>>>(x, kern, sx, sk, bias, out);
}